// Round 7
// baseline (599.998 us; speedup 1.0000x reference)
//
#include <hip/hip_runtime.h>
#include <hip/hip_fp16.h>

// ScalingAndSquaring: v <- v + warp(v), 7 steps, (2,3,160,160,160) f32.
// out(d,h,w) = v(d,h,w) + trilinear v(z~w, y~h, x~d)  (self-transposed gather).
// Round 7: empirical law from rounds 1-6: dur ~= FETCH_SIZE / 1.1 TB/s
// (constant across 6 structures; writes/instrs/MLP all free). fp16 (r6)
// didn't cut FETCH because a 128B line's gather-sharers (ia in {i,i+1},
// h0 +-6, ic +-1) straddled ~2.4 XCDs under (bat,ia,h0,ic) chunking.
// New decode: XCD owns a contiguous slab of p = ic*160 + h0 (the gather's
// (z,y) region) for ALL (bat,ia) -> line sharers land on one XCD; the 10
// (bat,ia) blocks of one (ic,h0) are dispatch-adjacent (concurrent reuse).

constexpr int SZ  = 160;
constexpr int HW  = SZ * SZ;          // 25600
constexpr int DHW = SZ * SZ * SZ;     // 4096000
constexpr size_t HALFVOL = (size_t)2 * 3 * DHW * sizeof(__half); // 49,152,000 B

typedef float vfloat4 __attribute__((ext_vector_type(4)));
typedef float vfloat2 __attribute__((ext_vector_type(2)));
typedef unsigned int vuint2 __attribute__((ext_vector_type(2)));

__device__ __forceinline__ float h2f(unsigned int u16) {
    return __half2float(__ushort_as_half((unsigned short)u16));
}
__device__ __forceinline__ unsigned int f2h(float f) {
    return (unsigned int)__half_as_ushort(__float2half(f));
}

template <typename TIN, typename TOUT>
__global__ __launch_bounds__(256, 3)
void warp_step(const TIN* __restrict__ src, TOUT* __restrict__ dst,
               float inScale)
{
    // --- XCD-by-gather-region decode (assumes round-robin xcd = wg % 8) ---
    const int wg  = (int)blockIdx.x;   // 0..7999
    const int xcd = wg & 7;
    const int q   = wg >> 3;           // 0..999 within XCD
    const int bi  = q % 10;            // (bat, ia) — fastest: concurrent sharers
    const int bat = bi % 2;
    const int ia  = bi / 2;            // 0..4
    const int pp  = q / 10;            // 0..99
    const int p   = xcd * 100 + pp;    // 0..799 = ic*160 + h0
    const int ic  = p / 160;           // 0..4
    const int h0  = p % 160;
    const int a0  = ia * 32;           // D-axis tile base
    const int c0  = ic * 32;           // W-axis tile base

    const TIN*  __restrict__ vb = src + (size_t)bat * 3 * DHW;
    TOUT*       __restrict__ db = dst + (size_t)bat * 3 * DHW;

    // tile[ch][w_local][d_local], stride 33 -> conflict-free both phases
    __shared__ float tile[3][32][33];
    const int tid = (int)threadIdx.x;

    // --- phase 1: stage own-voxel tile (scaled) as f32, coalesced reads ---
    if constexpr (sizeof(TIN) == 4) {
        const int q4 = (tid & 7) << 2;   // w_local quad base
        const int r0 = tid >> 3;         // d_local
        #pragma unroll
        for (int ch = 0; ch < 3; ++ch) {
            const vfloat4 vv = *reinterpret_cast<const vfloat4*>(
                &vb[ch * DHW + (a0 + r0) * HW + h0 * SZ + c0 + q4]);
            tile[ch][q4 + 0][r0] = vv.x * inScale;
            tile[ch][q4 + 1][r0] = vv.y * inScale;
            tile[ch][q4 + 2][r0] = vv.z * inScale;
            tile[ch][q4 + 3][r0] = vv.w * inScale;
        }
    } else {
        const int q4 = (tid & 7) << 2;   // 4 halves per thread
        const int r0 = tid >> 3;
        #pragma unroll
        for (int ch = 0; ch < 3; ++ch) {
            const vuint2 u = *reinterpret_cast<const vuint2*>(
                &vb[ch * DHW + (a0 + r0) * HW + h0 * SZ + c0 + q4]);
            tile[ch][q4 + 0][r0] = h2f(u.x & 0xffffu) * inScale;
            tile[ch][q4 + 1][r0] = h2f(u.x >> 16)     * inScale;
            tile[ch][q4 + 2][r0] = h2f(u.y & 0xffffu) * inScale;
            tile[ch][q4 + 3][r0] = h2f(u.y >> 16)     * inScale;
        }
    }
    __syncthreads();

    // --- phase 2: d-fast lanes; 4 samples/thread ---
    const int a  = tid & 31;      // d_local (lane-fast)
    const int cb = tid >> 5;      // 0..7    (w_local base)
    const float gx = (float)(a0 + a);   // d feeds grid_sample's x slot
    const float gy = (float)h0;         // h feeds y slot

    float v0s[4], v1s[4], v2s[4];
    int   ro[4][4];                     // row offsets (z,y corners)
    int   xb[4], idxs[4];               // pair base element, select index
    float wxs[4], wys[4], wzs[4];
    #pragma unroll
    for (int i = 0; i < 4; ++i) {
        const int c = cb + (i << 3);
        v0s[i] = tile[0][c][a];
        v1s[i] = tile[1][c][a];
        v2s[i] = tile[2][c][a];
        const float gz = (float)(c0 + c);
        float ix = ((2.0f * ((gx + v0s[i]) / 159.0f - 0.5f) + 1.0f) * 160.0f - 1.0f) * 0.5f;
        float iy = ((2.0f * ((gy + v1s[i]) / 159.0f - 0.5f) + 1.0f) * 160.0f - 1.0f) * 0.5f;
        float iz = ((2.0f * ((gz + v2s[i]) / 159.0f - 0.5f) + 1.0f) * 160.0f - 1.0f) * 0.5f;
        ix = fminf(fmaxf(ix, 0.0f), 159.0f);
        iy = fminf(fmaxf(iy, 0.0f), 159.0f);
        iz = fminf(fmaxf(iz, 0.0f), 159.0f);
        const float fy = floorf(iy), fz = floorf(iz);
        const int x0 = (int)floorf(ix);
        const int y0 = (int)fy, z0 = (int)fz;
        const int y1 = min(y0 + 1, SZ - 1);
        const int z1 = min(z0 + 1, SZ - 1);
        // corner-pair trick: xp=min(x0,158), wx'=ix-xp; at ix==159.0 wx'==1
        // selects the high element exactly. No OOB, no selects.
        const int xp = min(x0, SZ - 2);
        ro[i][0] = (z0 * SZ + y0) * SZ;
        ro[i][1] = (z0 * SZ + y1) * SZ;
        ro[i][2] = (z1 * SZ + y0) * SZ;
        ro[i][3] = (z1 * SZ + y1) * SZ;
        if constexpr (sizeof(TIN) == 4) {
            xb[i]   = xp;               // dwordx2 directly at xp
            idxs[i] = 0;
        } else {
            const int e = min(xp & ~1, SZ - 4);   // 4B-aligned 4-half window
            xb[i]   = e;                          // covers e..e+3 >= {xp,xp+1}
            idxs[i] = xp - e;                     // 0,1,2
        }
        wxs[i] = ix - (float)xp;
        wys[i] = iy - fy;
        wzs[i] = iz - fz;
    }

    // --- stage C: issue ALL 48 pair loads via asm, then one wait ---
    vfloat2 PF[4][3][4];
    vuint2  PH[4][3][4];
    #pragma unroll
    for (int i = 0; i < 4; ++i) {
        #pragma unroll
        for (int ch = 0; ch < 3; ++ch) {
            #pragma unroll
            for (int k = 0; k < 4; ++k) {
                const TIN* ptr = vb + ch * DHW + ro[i][k] + xb[i];
                if constexpr (sizeof(TIN) == 4)
                    asm volatile("global_load_dwordx2 %0, %1, off"
                                 : "=v"(PF[i][ch][k]) : "v"(ptr));
                else
                    asm volatile("global_load_dwordx2 %0, %1, off"
                                 : "=v"(PH[i][ch][k]) : "v"(ptr));
            }
        }
    }
    asm volatile("s_waitcnt vmcnt(0)" ::: "memory");
    __builtin_amdgcn_sched_barrier(0);   // rule #18: keep consumers below

    // --- interpolate + write back to own LDS slots ---
    #pragma unroll
    for (int i = 0; i < 4; ++i) {
        const int c = cb + (i << 3);
        const float wx = wxs[i], wy = wys[i], wz = wzs[i];
        const float wy0 = 1.0f - wy, wz0 = 1.0f - wz;
        const float w00 = wz0 * wy0, w01 = wz0 * wy;
        const float w10 = wz  * wy0, w11 = wz  * wy;
        const int idx = idxs[i];
        #pragma unroll
        for (int ch = 0; ch < 3; ++ch) {
            float s[4];
            #pragma unroll
            for (int k = 0; k < 4; ++k) {
                float lo, hi;
                if constexpr (sizeof(TIN) == 4) {
                    lo = PF[i][ch][k].x;
                    hi = PF[i][ch][k].y;
                } else {
                    const vuint2 u = PH[i][ch][k];
                    const unsigned int mid = (u.x >> 16) | (u.y << 16);
                    const unsigned int sel =
                        (idx & 1) ? mid : (idx ? u.y : u.x);
                    lo = h2f(sel & 0xffffu);
                    hi = h2f(sel >> 16);
                }
                s[k] = lo + wx * (hi - lo);
            }
            const float res = (s[0] * w00 + s[1] * w01)
                            + (s[2] * w10 + s[3] * w11);
            const float own = (ch == 0) ? v0s[i] : (ch == 1) ? v1s[i] : v2s[i];
            tile[ch][c][a] = own + res * inScale;
        }
    }
    __syncthreads();

    // --- phase 3: coalesced nontemporal writes ---
    if constexpr (sizeof(TOUT) == 4) {
        const int q4 = (tid & 7) << 2;
        const int r0 = tid >> 3;
        #pragma unroll
        for (int ch = 0; ch < 3; ++ch) {
            vfloat4 vv;
            vv.x = tile[ch][q4 + 0][r0];
            vv.y = tile[ch][q4 + 1][r0];
            vv.z = tile[ch][q4 + 2][r0];
            vv.w = tile[ch][q4 + 3][r0];
            __builtin_nontemporal_store(vv, reinterpret_cast<vfloat4*>(
                &db[ch * DHW + (a0 + r0) * HW + h0 * SZ + c0 + q4]));
        }
    } else {
        const int q4 = (tid & 7) << 2;
        const int r0 = tid >> 3;
        #pragma unroll
        for (int ch = 0; ch < 3; ++ch) {
            vuint2 u;
            u.x = f2h(tile[ch][q4 + 0][r0]) | (f2h(tile[ch][q4 + 1][r0]) << 16);
            u.y = f2h(tile[ch][q4 + 2][r0]) | (f2h(tile[ch][q4 + 3][r0]) << 16);
            __builtin_nontemporal_store(u, reinterpret_cast<vuint2*>(
                &db[ch * DHW + (a0 + r0) * HW + h0 * SZ + c0 + q4]));
        }
    }
}

extern "C" void kernel_launch(void* const* d_in, const int* in_sizes, int n_in,
                              void* d_out, int out_size, void* d_ws, size_t ws_size,
                              hipStream_t stream)
{
    const float* vin = (const float*)d_in[0];
    float* out = (float*)d_out;
    __half* A = (__half*)d_ws;                          // fp16 volume 0
    __half* B = (__half*)((char*)d_ws + HALFVOL);       // fp16 volume 1
    // ws needs 2 * 49,152,000 B = 98,304,000 B (same as the f32 ping-pong).

    dim3 grid(8000), block(256);
    warp_step<float,  __half><<<grid, block, 0, stream>>>(vin, A, 1.0f / 128.0f); // v1
    warp_step<__half, __half><<<grid, block, 0, stream>>>(A, B, 1.0f);            // v2
    warp_step<__half, __half><<<grid, block, 0, stream>>>(B, A, 1.0f);            // v3
    warp_step<__half, __half><<<grid, block, 0, stream>>>(A, B, 1.0f);            // v4
    warp_step<__half, __half><<<grid, block, 0, stream>>>(B, A, 1.0f);            // v5
    warp_step<__half, __half><<<grid, block, 0, stream>>>(A, B, 1.0f);            // v6
    warp_step<__half, float ><<<grid, block, 0, stream>>>(B, out, 1.0f);          // v7
}